// Round 5
// baseline (311.330 us; speedup 1.0000x reference)
//
#include <hip/hip_runtime.h>
#include <hip/hip_bf16.h>
#include <stdint.h>

#define P_B 4096
#define P_N 16384
#define P_F 768
#define P_E 512
#define NKT_F 24   // 768/32 k-tiles
#define NKT_E 16   // 512/32 k-tiles

typedef __attribute__((ext_vector_type(8))) __bf16 bf16x8;
typedef __attribute__((ext_vector_type(4))) float f32x4;

__device__ __forceinline__ unsigned short bfbits(float x) {
    __bf16 h = (__bf16)x;
    union { __bf16 h; unsigned short u; } cv;
    cv.h = h;
    return cv.u;
}
__device__ __forceinline__ float bf2f(unsigned short u) {
    union { float f; unsigned int i; } cv;
    cv.i = ((unsigned int)u) << 16;
    return cv.f;
}

// Fragment-packed layout for the echo GEMM operand (E=512 k-dim):
// element (r,k) -> (((r>>4)*NKT_E + (k>>5))*64 + ((k>>3)&3)*16 + (r&15))*8 + (k&7)
// One wave fragment = contiguous 1KB, lane-linear -> coalesced, no LDS.
__device__ __forceinline__ size_t pk16(int r, int k) {
    return ((size_t)((r >> 4) * NKT_E + (k >> 5)) * 64 + ((k >> 3) & 3) * 16 + (r & 15)) * 8 + (k & 7);
}

// ---------------------------------------------------------------------------
// Embed (direct): emb[row][col] = xd[row]·gw[col] + gb[col], reading fp32
// X/D/gw straight from global (no pack pass), converting to bf16 in-register.
// Barrier-free, LDS-free. Epilogue stores packed bf16 embedding + row ssq.
// Grid: 640 blocks 1D; bid&7 = XCD owns 20 rowTiles, colTile fastest so the
// fp32 A-slab is read once and gw stays L2-resident.
// ---------------------------------------------------------------------------
__global__ __launch_bounds__(256, 2) void embed_kernel(
    const float* __restrict__ X, const float* __restrict__ D,
    const float* __restrict__ gw, const float* __restrict__ gb,
    unsigned short* __restrict__ embpk, float* __restrict__ norm2)
{
    const int tid = threadIdx.x, lane = tid & 63, wave = tid >> 6;
    const int q = lane >> 4, c = lane & 15;
    const int bid = blockIdx.x;                        // 0..639
    const int rowTile = (bid & 7) * 20 + (bid >> 5);   // 0..159
    const int colTile = (bid >> 3) & 3;                // 0..3
    const int rowG0 = rowTile * 128;
    const int col0 = colTile * 128;
    const int wrow = (wave >> 1) * 64;
    const int wcol = (wave & 1) * 64;

    const float* srcbase;
    int localRow0;
    if (rowTile < 32) { srcbase = X; localRow0 = rowG0; }
    else              { srcbase = D; localRow0 = rowG0 - P_B; }

    const float* fa[4];
    const float* fb[4];
#pragma unroll
    for (int i = 0; i < 4; i++)
        fa[i] = srcbase + (size_t)(localRow0 + wrow + i * 16 + c) * P_F + q * 8;
#pragma unroll
    for (int j = 0; j < 4; j++)
        fb[j] = gw + (size_t)(col0 + wcol + j * 16 + c) * P_F + q * 8;

    f32x4 acc[4][4];
    const f32x4 zero = {0.f, 0.f, 0.f, 0.f};
#pragma unroll
    for (int i = 0; i < 4; i++)
#pragma unroll
        for (int j = 0; j < 4; j++) acc[i][j] = zero;

#pragma unroll
    for (int kt = 0; kt < NKT_F; ++kt) {
        bf16x8 af[4], bfr[4];
#pragma unroll
        for (int i = 0; i < 4; i++) {
            const float4 lo = *(const float4*)(fa[i] + kt * 32);
            const float4 hi = *(const float4*)(fa[i] + kt * 32 + 4);
            af[i][0] = (__bf16)lo.x; af[i][1] = (__bf16)lo.y;
            af[i][2] = (__bf16)lo.z; af[i][3] = (__bf16)lo.w;
            af[i][4] = (__bf16)hi.x; af[i][5] = (__bf16)hi.y;
            af[i][6] = (__bf16)hi.z; af[i][7] = (__bf16)hi.w;
        }
#pragma unroll
        for (int j = 0; j < 4; j++) {
            const float4 lo = *(const float4*)(fb[j] + kt * 32);
            const float4 hi = *(const float4*)(fb[j] + kt * 32 + 4);
            bfr[j][0] = (__bf16)lo.x; bfr[j][1] = (__bf16)lo.y;
            bfr[j][2] = (__bf16)lo.z; bfr[j][3] = (__bf16)lo.w;
            bfr[j][4] = (__bf16)hi.x; bfr[j][5] = (__bf16)hi.y;
            bfr[j][6] = (__bf16)hi.z; bfr[j][7] = (__bf16)hi.w;
        }
#pragma unroll
        for (int i = 0; i < 4; i++)
#pragma unroll
            for (int j = 0; j < 4; j++)
                acc[i][j] = __builtin_amdgcn_mfma_f32_16x16x32_bf16(af[i], bfr[j], acc[i][j], 0, 0, 0);
    }

    // epilogue: bias, packed bf16 store, row-wise sum of squares
    float ss[4][4];
#pragma unroll
    for (int i = 0; i < 4; i++)
#pragma unroll
        for (int r = 0; r < 4; r++) ss[i][r] = 0.f;
#pragma unroll
    for (int j = 0; j < 4; j++) {
        const int colg = col0 + wcol + j * 16 + c;
        const float bias = gb[colg];
#pragma unroll
        for (int i = 0; i < 4; i++) {
#pragma unroll
            for (int r = 0; r < 4; r++) {
                const int rowg = rowG0 + wrow + i * 16 + q * 4 + r;
                const float v = acc[i][j][r] + bias;
                const unsigned short hb = bfbits(v);
                embpk[pk16(rowg, colg)] = hb;
                const float vs = bf2f(hb);
                ss[i][r] = fmaf(vs, vs, ss[i][r]);
            }
        }
    }
#pragma unroll
    for (int i = 0; i < 4; i++)
#pragma unroll
        for (int r = 0; r < 4; r++) {
            float s = ss[i][r];
            s += __shfl_xor(s, 1);
            s += __shfl_xor(s, 2);
            s += __shfl_xor(s, 4);
            s += __shfl_xor(s, 8);
            ss[i][r] = s;
        }
    if (c == 0) {
#pragma unroll
        for (int i = 0; i < 4; i++)
#pragma unroll
            for (int r = 0; r < 4; r++) {
                const int rowg = rowG0 + wrow + i * 16 + q * 4 + r;
                atomicAdd(&norm2[rowg], ss[i][r]);
            }
    }
}

// ---------------------------------------------------------------------------
// Finalize: norm2[i] -> inv_norm^3 (X rows), inv_norm^3 * (2r-1) (D rows)
// ---------------------------------------------------------------------------
__global__ void finalize_kernel(float* __restrict__ nf, const float* __restrict__ r)
{
    const int i = blockIdx.x * 256 + threadIdx.x;
    if (i >= P_B + P_N) return;
    float nrm = sqrtf(nf[i]);
    nrm = fmaxf(nrm, 1e-12f);
    const float inv = 1.0f / nrm;
    float w = inv * inv * inv;
    if (i >= P_B) {
        const float rv = r[i - P_B];
        w *= (2.0f * rv - 1.0f);
    }
    nf[i] = w;
}

// ---------------------------------------------------------------------------
// Echo (packed, XCD-swizzled): barrier-free, LDS-free fragment GEMM.
// bid&7 = XCD owns 4 btiles (A-slab 512KB, L2-resident) and streams ntiles;
// 4 consecutive per-XCD blocks share one ntile (B temporal reuse).
// ---------------------------------------------------------------------------
__global__ __launch_bounds__(256, 2) void echo_pk_kernel(
    const unsigned short* __restrict__ embpk, const float* __restrict__ fbuf,
    float* __restrict__ echo)
{
    const int tid = threadIdx.x, lane = tid & 63, wave = tid >> 6;
    const int q = lane >> 4, c = lane & 15;
    const int bid = blockIdx.x;          // 0..4095
    const int idx = bid >> 3;            // 0..511
    const int btile = (bid & 7) * 4 + (idx & 3);   // 0..31
    const int ntile = idx >> 2;                    // 0..127
    const int row0 = btile * 128;
    const int col0 = ntile * 128;
    const int rbA0 = btile * 8 + (wave >> 1) * 4;
    const int rbB0 = 256 + ntile * 8 + (wave & 1) * 4;   // De rows start at rb 256

    const unsigned short* pa[4];
    const unsigned short* pb[4];
#pragma unroll
    for (int i = 0; i < 4; i++)
        pa[i] = embpk + ((size_t)(rbA0 + i) * NKT_E * 64 + lane) * 8;
#pragma unroll
    for (int j = 0; j < 4; j++)
        pb[j] = embpk + ((size_t)(rbB0 + j) * NKT_E * 64 + lane) * 8;

    f32x4 acc[4][4];
    const f32x4 zero = {0.f, 0.f, 0.f, 0.f};
#pragma unroll
    for (int i = 0; i < 4; i++)
#pragma unroll
        for (int j = 0; j < 4; j++) acc[i][j] = zero;

#pragma unroll
    for (int kt = 0; kt < NKT_E; ++kt) {
        bf16x8 af[4], bfr[4];
#pragma unroll
        for (int i = 0; i < 4; i++) af[i] = *(const bf16x8*)(pa[i] + (size_t)kt * 512);
#pragma unroll
        for (int j = 0; j < 4; j++) bfr[j] = *(const bf16x8*)(pb[j] + (size_t)kt * 512);
#pragma unroll
        for (int i = 0; i < 4; i++)
#pragma unroll
            for (int j = 0; j < 4; j++)
                acc[i][j] = __builtin_amdgcn_mfma_f32_16x16x32_bf16(af[i], bfr[j], acc[i][j], 0, 0, 0);
    }

    // epilogue: cube, weight by (ind^3*r2), reduce over columns, atomicAdd rows
    const float* fX = fbuf;
    const float* fD = fbuf + P_B;
    float wc[4];
#pragma unroll
    for (int j = 0; j < 4; j++) wc[j] = fD[col0 + (wave & 1) * 64 + j * 16 + c];
    float p[4][4];
#pragma unroll
    for (int i = 0; i < 4; i++)
#pragma unroll
        for (int r = 0; r < 4; r++) p[i][r] = 0.f;
#pragma unroll
    for (int i = 0; i < 4; i++)
#pragma unroll
        for (int j = 0; j < 4; j++)
#pragma unroll
            for (int r = 0; r < 4; r++) {
                const float v = acc[i][j][r];
                const float v3 = v * v * v;
                p[i][r] = fmaf(v3, wc[j], p[i][r]);
            }
#pragma unroll
    for (int i = 0; i < 4; i++)
#pragma unroll
        for (int r = 0; r < 4; r++) {
            float s = p[i][r];
            s += __shfl_xor(s, 1);
            s += __shfl_xor(s, 2);
            s += __shfl_xor(s, 4);
            s += __shfl_xor(s, 8);
            p[i][r] = s;
        }
    if (c == 0) {
#pragma unroll
        for (int i = 0; i < 4; i++)
#pragma unroll
            for (int r = 0; r < 4; r++) {
                const int rowg = row0 + (wave >> 1) * 64 + i * 16 + q * 4 + r;
                atomicAdd(&echo[rowg], p[i][r] * fX[rowg]);
            }
    }
}

// ---------------------------------------------------------------------------
// Head: logits = echo*h_w + h_b ; preds = sigmoid(logits)
// ---------------------------------------------------------------------------
__global__ void head_kernel(const float* __restrict__ echo, const float* __restrict__ hw,
                            const float* __restrict__ hb, float* __restrict__ out)
{
    const int i = blockIdx.x * 256 + threadIdx.x;
    if (i >= P_B) return;
    const float logit = fmaf(echo[i], hw[0], hb[0]);
    out[i] = logit;
    out[P_B + i] = 1.0f / (1.0f + expf(-logit));
}

extern "C" void kernel_launch(void* const* d_in, const int* in_sizes, int n_in,
                              void* d_out, int out_size, void* d_ws, size_t ws_size,
                              hipStream_t stream)
{
    const float* X  = (const float*)d_in[0];
    const float* D  = (const float*)d_in[1];
    const float* r  = (const float*)d_in[2];
    const float* gw = (const float*)d_in[3];
    const float* gb = (const float*)d_in[4];
    const float* hw = (const float*)d_in[5];
    const float* hb = (const float*)d_in[6];
    float* out = (float*)d_out;

    char* ws = (char*)d_ws;
    // layout: embpk bf16 packed [1280 rb][16 kt][64 lane][8] | norm2/f [20480] | echo [4096]
    const size_t embpk_bytes = (size_t)1280 * NKT_E * 64 * 8 * 2;   // 20,971,520
    const size_t tail_bytes  = (size_t)(P_B + P_N + P_B) * sizeof(float);
    unsigned short* embpk = (unsigned short*)ws;
    float* norm2 = (float*)(ws + embpk_bytes);
    float* echo = norm2 + (P_B + P_N);

    hipMemsetAsync(norm2, 0, tail_bytes, stream);

    embed_kernel<<<dim3(640), 256, 0, stream>>>(X, D, gw, gb, embpk, norm2);
    finalize_kernel<<<dim3((P_B + P_N + 255) / 256), 256, 0, stream>>>(norm2, r);
    echo_pk_kernel<<<dim3(4096), 256, 0, stream>>>(embpk, norm2, echo);
    head_kernel<<<dim3((P_B + 255) / 256), 256, 0, stream>>>(echo, hw, hb, out);
}

// Round 6
// 225.856 us; speedup vs baseline: 1.3784x; 1.3784x over previous
//
#include <hip/hip_runtime.h>
#include <hip/hip_bf16.h>
#include <stdint.h>

#define P_B 4096
#define P_N 16384
#define P_F 768
#define P_E 512
#define NKT_F 24   // 768/32 k-tiles
#define NKT_E 16   // 512/32 k-tiles
#define CPAD 776   // convert LDS row pad (bf16 elems): 1552B stride -> <=2-way banks
#define EPAD 136   // embed epilogue LDS row pad: 272B stride, 16B-aligned rows

typedef __attribute__((ext_vector_type(8))) __bf16 bf16x8;
typedef __attribute__((ext_vector_type(4))) float f32x4;

__device__ __forceinline__ unsigned short bfbits(float x) {
    __bf16 h = (__bf16)x;
    union { __bf16 h; unsigned short u; } cv;
    cv.h = h;
    return cv.u;
}
__device__ __forceinline__ float bf2f(unsigned short u) {
    union { float f; unsigned int i; } cv;
    cv.i = ((unsigned int)u) << 16;
    return cv.f;
}

// Fragment-packed layout: element (r,k) of a [R][K] bf16 matrix lives at
//   (((r>>4)*NKT + (k>>5))*64 + ((k>>3)&3)*16 + (r&15))*8 + (k&7)
// One wave fragment = contiguous 1KB, lane-linear -> coalesced, no LDS in GEMM.

// ---------------------------------------------------------------------------
// Convert+pack v2: fp32 row-major -> bf16 fragment-packed, coalesced on BOTH
// sides via an LDS transpose. One block = 16 rows x 768 K.
// Blocks 0..255 = X, 256..1279 = D, 1280..1311 = gw.
// ---------------------------------------------------------------------------
__global__ __launch_bounds__(256) void convert_pack_kernel(
    const float* __restrict__ X, const float* __restrict__ D,
    const float* __restrict__ gw,
    unsigned short* __restrict__ xdpk, unsigned short* __restrict__ gwpk)
{
    __shared__ unsigned short T[16 * CPAD];
    const int tid = threadIdx.x;
    const int rb = blockIdx.x;          // 0..1311
    const float* src;
    unsigned short* dstbase;
    if (rb < 256)       { src = X  + (size_t)rb * 16 * P_F;          dstbase = xdpk + (size_t)rb * NKT_F * 1024 / 2 * 1; }
    else if (rb < 1280) { src = D  + (size_t)(rb - 256) * 16 * P_F;  dstbase = xdpk + (size_t)rb * NKT_F * 512; }
    else                { src = gw + (size_t)(rb - 1280) * 16 * P_F; dstbase = gwpk + (size_t)(rb - 1280) * NKT_F * 512; }
    if (rb < 256) dstbase = xdpk + (size_t)rb * NKT_F * 512;  // (512 ushort = 1KB per kt)

    // coalesced read: 16*768 floats = 12 iters of 1024 floats
#pragma unroll
    for (int it = 0; it < 12; ++it) {
        const int flat = it * 1024 + tid * 4;
        const int row = flat / P_F;
        const int col = flat - row * P_F;
        const float4 v = *(const float4*)(src + (size_t)row * P_F + col);
        unsigned short* t = &T[row * CPAD + col];
        t[0] = bfbits(v.x); t[1] = bfbits(v.y); t[2] = bfbits(v.z); t[3] = bfbits(v.w);
    }
    __syncthreads();

    // packed write: 24 kt x 64 lanes x 16B = 1536 chunks, 6 iters
#pragma unroll
    for (int it = 0; it < 6; ++it) {
        const int m = it * 256 + tid;
        const int kt = m >> 6;          // 0..23
        const int lane = m & 63;
        const int r = lane & 15;
        const int k = kt * 32 + (lane >> 4) * 8;
        const uint4 frag = *(const uint4*)(&T[r * CPAD + k]);
        *(uint4*)(dstbase + (size_t)(kt * 64 + lane) * 8) = frag;
    }
}

// ---------------------------------------------------------------------------
// Embed (packed): emb = xd·gw^T + gb. Barrier-free K-loop on packed fragments
// (r4-proven). Epilogue: LDS transpose -> coalesced packed stores (replaces
// the r4 2-byte scatter), + per-row sum-of-squares.
// ---------------------------------------------------------------------------
__global__ __launch_bounds__(256, 2) void embed_pk_kernel(
    const unsigned short* __restrict__ xdpk, const unsigned short* __restrict__ gwpk,
    const float* __restrict__ gb,
    unsigned short* __restrict__ embpk, float* __restrict__ norm2)
{
    __shared__ unsigned short Es[128 * EPAD];
    const int tid = threadIdx.x, lane = tid & 63, wave = tid >> 6;
    const int q = lane >> 4, c = lane & 15;
    const int colTile = blockIdx.x;   // 0..3
    const int rowTile = blockIdx.y;   // 0..159
    const int rbA0 = rowTile * 8 + (wave >> 1) * 4;
    const int rbB0 = colTile * 8 + (wave & 1) * 4;

    const unsigned short* pa[4];
    const unsigned short* pb[4];
#pragma unroll
    for (int i = 0; i < 4; i++)
        pa[i] = xdpk + ((size_t)(rbA0 + i) * NKT_F * 64 + lane) * 8;
#pragma unroll
    for (int j = 0; j < 4; j++)
        pb[j] = gwpk + ((size_t)(rbB0 + j) * NKT_F * 64 + lane) * 8;

    f32x4 acc[4][4];
    const f32x4 zero = {0.f, 0.f, 0.f, 0.f};
#pragma unroll
    for (int i = 0; i < 4; i++)
#pragma unroll
        for (int j = 0; j < 4; j++) acc[i][j] = zero;

#pragma unroll
    for (int kt = 0; kt < NKT_F; ++kt) {
        bf16x8 af[4], bfr[4];
#pragma unroll
        for (int i = 0; i < 4; i++) af[i] = *(const bf16x8*)(pa[i] + (size_t)kt * 512);
#pragma unroll
        for (int j = 0; j < 4; j++) bfr[j] = *(const bf16x8*)(pb[j] + (size_t)kt * 512);
#pragma unroll
        for (int i = 0; i < 4; i++)
#pragma unroll
            for (int j = 0; j < 4; j++)
                acc[i][j] = __builtin_amdgcn_mfma_f32_16x16x32_bf16(af[i], bfr[j], acc[i][j], 0, 0, 0);
    }

    // epilogue: bias, ssq, LDS row-major stash (conflict-free: 16 lanes x 32B
    // contiguous, q-groups land 8 banks apart)
    float ss[4][4];
#pragma unroll
    for (int i = 0; i < 4; i++)
#pragma unroll
        for (int r = 0; r < 4; r++) ss[i][r] = 0.f;
#pragma unroll
    for (int j = 0; j < 4; j++) {
        const int lcbase = (wave & 1) * 64 + j * 16 + c;
        const float bias = gb[colTile * 128 + lcbase];
#pragma unroll
        for (int i = 0; i < 4; i++) {
#pragma unroll
            for (int r = 0; r < 4; r++) {
                const int lr = (wave >> 1) * 64 + i * 16 + q * 4 + r;
                const float v = acc[i][j][r] + bias;
                const unsigned short hb = bfbits(v);
                Es[lr * EPAD + lcbase] = hb;
                const float vs = bf2f(hb);
                ss[i][r] = fmaf(vs, vs, ss[i][r]);
            }
        }
    }
#pragma unroll
    for (int i = 0; i < 4; i++)
#pragma unroll
        for (int r = 0; r < 4; r++) {
            float s = ss[i][r];
            s += __shfl_xor(s, 1);
            s += __shfl_xor(s, 2);
            s += __shfl_xor(s, 4);
            s += __shfl_xor(s, 8);
            ss[i][r] = s;
        }
    if (c == 0) {
#pragma unroll
        for (int i = 0; i < 4; i++)
#pragma unroll
            for (int r = 0; r < 4; r++) {
                const int rowg = rowTile * 128 + (wave >> 1) * 64 + i * 16 + q * 4 + r;
                atomicAdd(&norm2[rowg], ss[i][r]);
            }
    }
    __syncthreads();

    // coalesced packed store: 8 rb x 4 kt x 64 lanes x 16B = 2048 chunks
#pragma unroll
    for (int it = 0; it < 8; ++it) {
        const int m = it * 256 + tid;
        const int rbl = m >> 8;             // 0..7
        const int rest = m & 255;
        const int ktl = rest >> 6;          // 0..3
        const int lane2 = rest & 63;
        const int r2 = lane2 & 15;
        const int q2 = lane2 >> 4;
        const int lr = rbl * 16 + r2;
        const int lc = ktl * 32 + q2 * 8;
        const uint4 frag = *(const uint4*)(&Es[lr * EPAD + lc]);
        const size_t rb = (size_t)(rowTile * 8 + rbl);
        const size_t kte = (size_t)(colTile * 4 + ktl);
        *(uint4*)(embpk + ((rb * NKT_E + kte) * 64 + lane2) * 8) = frag;
    }
}

// ---------------------------------------------------------------------------
// Finalize: norm2[i] -> inv_norm^3 (X rows), inv_norm^3 * (2r-1) (D rows)
// ---------------------------------------------------------------------------
__global__ void finalize_kernel(float* __restrict__ nf, const float* __restrict__ r)
{
    const int i = blockIdx.x * 256 + threadIdx.x;
    if (i >= P_B + P_N) return;
    float nrm = sqrtf(nf[i]);
    nrm = fmaxf(nrm, 1e-12f);
    const float inv = 1.0f / nrm;
    float w = inv * inv * inv;
    if (i >= P_B) {
        const float rv = r[i - P_B];
        w *= (2.0f * rv - 1.0f);
    }
    nf[i] = w;
}

// ---------------------------------------------------------------------------
// Echo (packed, r4-proven): barrier-free, LDS-free fragment GEMM with 8x8
// supertile swizzle. 96 us measured.
// ---------------------------------------------------------------------------
__global__ __launch_bounds__(256, 2) void echo_pk_kernel(
    const unsigned short* __restrict__ embpk, const float* __restrict__ fbuf,
    float* __restrict__ echo)
{
    const int tid = threadIdx.x, lane = tid & 63, wave = tid >> 6;
    const int q = lane >> 4, c = lane & 15;
    const int bid = blockIdx.x;          // 0..4095
    const int sb = bid >> 6, w = bid & 63;
    const int btile = (sb & 3) * 8 + (w & 7);    // 0..31
    const int ntile = (sb >> 2) * 8 + (w >> 3);  // 0..127
    const int row0 = btile * 128;
    const int col0 = ntile * 128;
    const int rbA0 = btile * 8 + (wave >> 1) * 4;
    const int rbB0 = 256 + ntile * 8 + (wave & 1) * 4;   // De rows start at rb 256

    const unsigned short* pa[4];
    const unsigned short* pb[4];
#pragma unroll
    for (int i = 0; i < 4; i++)
        pa[i] = embpk + ((size_t)(rbA0 + i) * NKT_E * 64 + lane) * 8;
#pragma unroll
    for (int j = 0; j < 4; j++)
        pb[j] = embpk + ((size_t)(rbB0 + j) * NKT_E * 64 + lane) * 8;

    f32x4 acc[4][4];
    const f32x4 zero = {0.f, 0.f, 0.f, 0.f};
#pragma unroll
    for (int i = 0; i < 4; i++)
#pragma unroll
        for (int j = 0; j < 4; j++) acc[i][j] = zero;

#pragma unroll
    for (int kt = 0; kt < NKT_E; ++kt) {
        bf16x8 af[4], bfr[4];
#pragma unroll
        for (int i = 0; i < 4; i++) af[i] = *(const bf16x8*)(pa[i] + (size_t)kt * 512);
#pragma unroll
        for (int j = 0; j < 4; j++) bfr[j] = *(const bf16x8*)(pb[j] + (size_t)kt * 512);
#pragma unroll
        for (int i = 0; i < 4; i++)
#pragma unroll
            for (int j = 0; j < 4; j++)
                acc[i][j] = __builtin_amdgcn_mfma_f32_16x16x32_bf16(af[i], bfr[j], acc[i][j], 0, 0, 0);
    }

    // epilogue: cube, weight by (ind^3*r2), reduce over columns, atomicAdd rows
    const float* fX = fbuf;
    const float* fD = fbuf + P_B;
    float wc[4];
#pragma unroll
    for (int j = 0; j < 4; j++) wc[j] = fD[col0 + (wave & 1) * 64 + j * 16 + c];
    float p[4][4];
#pragma unroll
    for (int i = 0; i < 4; i++)
#pragma unroll
        for (int r = 0; r < 4; r++) p[i][r] = 0.f;
#pragma unroll
    for (int i = 0; i < 4; i++)
#pragma unroll
        for (int j = 0; j < 4; j++)
#pragma unroll
            for (int r = 0; r < 4; r++) {
                const float v = acc[i][j][r];
                const float v3 = v * v * v;
                p[i][r] = fmaf(v3, wc[j], p[i][r]);
            }
#pragma unroll
    for (int i = 0; i < 4; i++)
#pragma unroll
        for (int r = 0; r < 4; r++) {
            float s = p[i][r];
            s += __shfl_xor(s, 1);
            s += __shfl_xor(s, 2);
            s += __shfl_xor(s, 4);
            s += __shfl_xor(s, 8);
            p[i][r] = s;
        }
    if (c == 0) {
#pragma unroll
        for (int i = 0; i < 4; i++)
#pragma unroll
            for (int r = 0; r < 4; r++) {
                const int rowg = row0 + (wave >> 1) * 64 + i * 16 + q * 4 + r;
                atomicAdd(&echo[rowg], p[i][r] * fX[rowg]);
            }
    }
}

// ---------------------------------------------------------------------------
// Head: logits = echo*h_w + h_b ; preds = sigmoid(logits)
// ---------------------------------------------------------------------------
__global__ void head_kernel(const float* __restrict__ echo, const float* __restrict__ hw,
                            const float* __restrict__ hb, float* __restrict__ out)
{
    const int i = blockIdx.x * 256 + threadIdx.x;
    if (i >= P_B) return;
    const float logit = fmaf(echo[i], hw[0], hb[0]);
    out[i] = logit;
    out[P_B + i] = 1.0f / (1.0f + expf(-logit));
}

extern "C" void kernel_launch(void* const* d_in, const int* in_sizes, int n_in,
                              void* d_out, int out_size, void* d_ws, size_t ws_size,
                              hipStream_t stream)
{
    const float* X  = (const float*)d_in[0];
    const float* D  = (const float*)d_in[1];
    const float* r  = (const float*)d_in[2];
    const float* gw = (const float*)d_in[3];
    const float* gb = (const float*)d_in[4];
    const float* hw = (const float*)d_in[5];
    const float* hb = (const float*)d_in[6];
    float* out = (float*)d_out;

    char* ws = (char*)d_ws;
    const size_t xdpk_bytes  = (size_t)1280 * NKT_F * 64 * 8 * 2;   // 31,457,280
    const size_t gwpk_bytes  = (size_t)32 * NKT_F * 64 * 8 * 2;     //    786,432
    const size_t embpk_bytes = (size_t)1280 * NKT_E * 64 * 8 * 2;   // 20,971,520
    const size_t tail_bytes  = (size_t)(P_B + P_N + P_B) * sizeof(float);

    unsigned short* xdpk  = (unsigned short*)ws;
    unsigned short* gwpk  = (unsigned short*)(ws + xdpk_bytes);
    unsigned short* embpk = (unsigned short*)(ws + xdpk_bytes + gwpk_bytes);
    float* norm2 = (float*)((char*)embpk + embpk_bytes);
    float* echo = norm2 + (P_B + P_N);

    hipMemsetAsync(norm2, 0, tail_bytes, stream);

    convert_pack_kernel<<<dim3(1312), 256, 0, stream>>>(X, D, gw, xdpk, gwpk);
    embed_pk_kernel<<<dim3(4, 160), 256, 0, stream>>>(xdpk, gwpk, gb, embpk, norm2);
    finalize_kernel<<<dim3((P_B + P_N + 255) / 256), 256, 0, stream>>>(norm2, r);
    echo_pk_kernel<<<dim3(4096), 256, 0, stream>>>(embpk, norm2, echo);
    head_kernel<<<dim3((P_B + 255) / 256), 256, 0, stream>>>(echo, hw, hb, out);
}